// Round 11
// baseline (176.661 us; speedup 1.0000x reference)
//
#include <hip/hip_runtime.h>
#include <hip/hip_bf16.h>
#include <math.h>

#define NTOK 512      // N
#define BATCH 2
#define HID 256
#define HEADS 4
#define HD 64
#define NEG_INF -1e9f

typedef short bf16x8 __attribute__((ext_vector_type(8)));
typedef short bf16x4 __attribute__((ext_vector_type(4)));
typedef float f32x4 __attribute__((ext_vector_type(4)));

__device__ __forceinline__ short f2bf(float f) {
    union { __hip_bfloat16 h; short s; } u;
    u.h = __float2bfloat16(f);
    return u.s;
}

// tanh-form gelu, exp2+rcp based (8 ops, 2 trans).
__device__ __forceinline__ float fast_gelu(float x) {
    const float x2 = x * x;
    const float u = x * fmaf(x2, 0.044715f, 1.0f);
    const float e = __builtin_amdgcn_exp2f(u * 2.3021176f);
    const float r = __builtin_amdgcn_rcpf(e + 1.0f);
    return fmaf(-x, r, x);
}

// ---------------------------------------------------------------------------
// Stage A: fused 5-way projection GEMM. 8-row tiles, grid (128,5).
//   Q/K/V stored bf16 (attn consumes bf16 anyway); A/BbT stay fp32.
// ---------------------------------------------------------------------------
__global__ __launch_bounds__(256) void pga_proj5(
    const float* __restrict__ x,
    const float* __restrict__ Wq, const float* __restrict__ bq,
    const float* __restrict__ Wk, const float* __restrict__ bk,
    const float* __restrict__ Wv, const float* __restrict__ bv,
    const float* __restrict__ Wp1, const float* __restrict__ bp1,
    unsigned short* __restrict__ Qb, unsigned short* __restrict__ Kb,
    unsigned short* __restrict__ Vb,
    float* __restrict__ A, float* __restrict__ BbT)
{
    __shared__ float xs[8][HID];
    const int m0 = blockIdx.x * 8;
    const int which = blockIdx.y;
    const int t = threadIdx.x;
    const int cg = t & 63;
    const int rg = t >> 6;

    {
        const float4* xg = (const float4*)(x + m0 * HID);
        float4* xsv = (float4*)xs;
        xsv[t] = xg[t];
        xsv[t + 256] = xg[t + 256];
    }
    __syncthreads();

    const float* W; const float* bvec;
    switch (which) {
        case 0: W = Wq; bvec = bq; break;
        case 1: W = Wk; bvec = bk; break;
        case 2: W = Wv; bvec = bv; break;
        case 3: W = Wp1; bvec = bp1; break;
        default: W = Wp1 + HID * HID; bvec = nullptr; break;
    }

    float4 bias4 = make_float4(0.f, 0.f, 0.f, 0.f);
    if (bvec) bias4 = ((const float4*)bvec)[cg];
    float4 acc[2] = {bias4, bias4};

    const float4* W4 = (const float4*)W;
    #pragma unroll 2
    for (int kq = 0; kq < 64; ++kq) {
        const float4 w0 = W4[(4 * kq + 0) * 64 + cg];
        const float4 w1 = W4[(4 * kq + 1) * 64 + cg];
        const float4 w2 = W4[(4 * kq + 2) * 64 + cg];
        const float4 w3 = W4[(4 * kq + 3) * 64 + cg];
        #pragma unroll
        for (int r = 0; r < 2; ++r) {
            const float4 xv = ((const float4*)xs[2 * rg + r])[kq];
            acc[r].x = fmaf(xv.x, w0.x, fmaf(xv.y, w1.x, fmaf(xv.z, w2.x, fmaf(xv.w, w3.x, acc[r].x))));
            acc[r].y = fmaf(xv.x, w0.y, fmaf(xv.y, w1.y, fmaf(xv.z, w2.y, fmaf(xv.w, w3.y, acc[r].y))));
            acc[r].z = fmaf(xv.x, w0.z, fmaf(xv.y, w1.z, fmaf(xv.z, w2.z, fmaf(xv.w, w3.z, acc[r].z))));
            acc[r].w = fmaf(xv.x, w0.w, fmaf(xv.y, w1.w, fmaf(xv.z, w2.w, fmaf(xv.w, w3.w, acc[r].w))));
        }
    }

    if (which < 3) {
        unsigned short* ob = (which == 0) ? Qb : (which == 1) ? Kb : Vb;
        #pragma unroll
        for (int r = 0; r < 2; ++r) {
            bf16x4 v;
            v[0] = f2bf(acc[r].x); v[1] = f2bf(acc[r].y);
            v[2] = f2bf(acc[r].z); v[3] = f2bf(acc[r].w);
            *(bf16x4*)&ob[(m0 + 2 * rg + r) * HID + 4 * cg] = v;
        }
    } else if (which == 3) {
        #pragma unroll
        for (int r = 0; r < 2; ++r)
            ((float4*)(A + (m0 + 2 * rg + r) * HID))[cg] = acc[r];
    } else {
        const int b = m0 >= NTOK;
        const int n0 = m0 - b * NTOK;
        #pragma unroll
        for (int r = 0; r < 2; ++r) {
            const int row = n0 + 2 * rg + r;
            float* ob = BbT + b * (HID * NTOK);
            ob[(4 * cg + 0) * NTOK + row] = acc[r].x;
            ob[(4 * cg + 1) * NTOK + row] = acc[r].y;
            ob[(4 * cg + 2) * NTOK + row] = acc[r].z;
            ob[(4 * cg + 3) * NTOK + row] = acc[r].w;
        }
    }
}

// ---------------------------------------------------------------------------
// Stage B: physics bias, split-d. ONE row per 640-thread block (10 waves).
//   Waves 0-4 compute d in [0,128), waves 5-9 d in [128,256) for the SAME
//   pair slots; partials combine via LDS. Doubles active waves per pair
//   (structural fix for the 4-waves/SIMD cap of 1-pair-per-lane).
//   NEG_INF baked into masked entries so attn reads no adj.
// ---------------------------------------------------------------------------
__global__ __launch_bounds__(640) void pga_bias(
    const float* __restrict__ A, const float* __restrict__ BbT,
    const float* __restrict__ Wp2, const float* __restrict__ bp2,
    const int* __restrict__ adj, float* __restrict__ biasg)
{
    __shared__ float as[HID];
    __shared__ float4 wp[HID];
    __shared__ short jlist[NTOK];
    __shared__ int ccnt[8];
    __shared__ float4 part[320];

    const int t = threadIdx.x;          // 0..639
    const int b = blockIdx.x >> 9;
    const int i = blockIdx.x & 511;
    const int w = t >> 6, lane = t & 63;
    const unsigned long long ltm = (1ull << lane) - 1ull;

    if (t < HID) {
        as[t] = A[(b * NTOK + i) * HID + t];
        wp[t] = ((const float4*)Wp2)[t];
    }

    float* const obase = biasg + (((size_t)b * HEADS) * NTOK + i) * NTOK;

    // ---- ordered ballot compaction (threads t<512 <-> j=t), NEG_INF bake ----
    const bool m = (t < NTOK) ? (adj[i * NTOK + t] > 0) : false;
    const unsigned long long bm = __ballot(m);
    if (w < 8 && lane == 0) ccnt[w] = __popcll(bm);
    if (w < 8 && !m) {
        float* o = obase + t;
        o[0 * NTOK * NTOK] = NEG_INF; o[1 * NTOK * NTOK] = NEG_INF;
        o[2 * NTOK * NTOK] = NEG_INF; o[3 * NTOK * NTOK] = NEG_INF;
    }
    __syncthreads();

    int pref = 0, tot = 0;
    #pragma unroll
    for (int c = 0; c < 8; ++c) {
        if (c == w) pref = tot;
        tot += ccnt[c];
    }
    if (m) jlist[pref + __popcll(bm & ltm)] = (short)t;
    __syncthreads();

    // ---- main: slot tl, d-half dh per thread; combine via LDS ----
    const int dh = t >= 320;
    const int tl = dh ? t - 320 : t;
    const float* bb = BbT + b * (HID * NTOK) + (dh ? 128 * NTOK : 0);
    const float* asr = as + (dh ? 128 : 0);
    const float4* wpr = wp + (dh ? 128 : 0);
    const float4 bp = *(const float4*)bp2;

    for (int base = 0; base < tot; base += 320) {
        const int idx = base + tl;
        float ah0 = 0.f, ah1 = 0.f, ah2 = 0.f, ah3 = 0.f;
        int j = 0;
        if (idx < tot) {
            j = jlist[idx];
            #pragma unroll 4
            for (int d = 0; d < 128; ++d) {
                const float g = fast_gelu(asr[d] + bb[d * NTOK + j]);
                const float4 wv = wpr[d];
                ah0 = fmaf(g, wv.x, ah0); ah1 = fmaf(g, wv.y, ah1);
                ah2 = fmaf(g, wv.z, ah2); ah3 = fmaf(g, wv.w, ah3);
            }
            if (dh) part[tl] = make_float4(ah0, ah1, ah2, ah3);
        }
        __syncthreads();
        if (!dh && idx < tot) {
            const float4 ph = part[tl];
            float* o = obase + j;
            o[0 * NTOK * NTOK] = ah0 + ph.x + bp.x;
            o[1 * NTOK * NTOK] = ah1 + ph.y + bp.y;
            o[2 * NTOK * NTOK] = ah2 + ph.z + bp.z;
            o[3 * NTOK * NTOK] = ah3 + ph.w + bp.w;
        }
        __syncthreads();
    }
}

// ---------------------------------------------------------------------------
// Stage C: MFMA attention, flash-decoding j-split. bf16 Q/K/V inputs:
//   Q frags = two direct 16B loads; K staged 16B, V staged 8B (no cvt).
//   Bias already contains NEG_INF at masked entries -> no adj read.
// ---------------------------------------------------------------------------
#define KT_STRIDE 72
#define VN_STRIDE 76
#define PL_STRIDE 136

__global__ __launch_bounds__(256) void pga_attn(
    const unsigned short* __restrict__ Qb, const unsigned short* __restrict__ Kb,
    const unsigned short* __restrict__ Vb, const float* __restrict__ biasg,
    float* __restrict__ op0, float* __restrict__ op1,
    float* __restrict__ op2, float* __restrict__ op3,
    float* __restrict__ mlbuf)
{
    __shared__ short Kt[128 * KT_STRIDE];
    __shared__ short Vn[128 * VN_STRIDE];
    __shared__ short Pl[4][16 * PL_STRIDE];

    const int blk = blockIdx.x;
    const int js = blk & 3;
    const int qt = (blk >> 2) & 7;
    const int h  = (blk >> 5) & 3;
    const int b  = blk >> 7;
    const int t = threadIdx.x;
    const int w = t >> 6;
    const int lane = t & 63;
    const int ln15 = lane & 15;
    const int quad = lane >> 4;

    float* Opart = (js == 0) ? op0 : (js == 1) ? op1 : (js == 2) ? op2 : op3;
    const int j0 = js * 128;
    const int i0w = qt * 64 + w * 16;

    // ---- Q A-fragments: two direct 16B bf16 loads ----
    const unsigned short* qrow = Qb + ((size_t)(b * NTOK) + i0w + ln15) * HID + h * HD;
    const bf16x8 aq0 = *(const bf16x8*)&qrow[quad * 8];
    const bf16x8 aq1 = *(const bf16x8*)&qrow[32 + quad * 8];

    // ---- stage K (16B copies) and V (8B copies) ----
    #pragma unroll
    for (int k = 0; k < 4; ++k) {
        const int flat8 = k * 256 + t;          // 1024 short8 = 128 rows x 8
        const int jl = flat8 >> 3, d8 = flat8 & 7;
        *(bf16x8*)&Kt[jl * KT_STRIDE + d8 * 8] =
            *(const bf16x8*)&Kb[((size_t)(b * NTOK) + j0 + jl) * HID + h * HD + d8 * 8];
    }
    #pragma unroll
    for (int k = 0; k < 8; ++k) {
        const int flat4 = k * 256 + t;          // 2048 short4 = 128 rows x 16
        const int jl = flat4 >> 4, d4 = flat4 & 15;
        *(bf16x4*)&Vn[jl * VN_STRIDE + d4 * 4] =
            *(const bf16x4*)&Vb[((size_t)(b * NTOK) + j0 + jl) * HID + h * HD + d4 * 4];
    }
    __syncthreads();

    // ---- S = (Q K^T) * scale + bias (bias has NEG_INF baked in) ----
    const float* bgb = biasg + ((size_t)(b * HEADS + h)) * NTOK * NTOK;
    f32x4 s[8];
    #pragma unroll
    for (int nt = 0; nt < 8; ++nt) {
        const int krow = nt * 16 + ln15;
        const bf16x8 bk0 = *(const bf16x8*)&Kt[krow * KT_STRIDE + quad * 8];
        const bf16x8 bk1 = *(const bf16x8*)&Kt[krow * KT_STRIDE + 32 + quad * 8];
        f32x4 acc = (f32x4){0.f, 0.f, 0.f, 0.f};
        acc = __builtin_amdgcn_mfma_f32_16x16x32_bf16(aq0, bk0, acc, 0, 0, 0);
        acc = __builtin_amdgcn_mfma_f32_16x16x32_bf16(aq1, bk1, acc, 0, 0, 0);
        const int j = j0 + nt * 16 + ln15;
        #pragma unroll
        for (int r = 0; r < 4; ++r) {
            const int i = i0w + quad * 4 + r;
            acc[r] = fmaf(acc[r], 0.125f, bgb[(size_t)i * NTOK + j]);
        }
        s[nt] = acc;
    }

    // ---- single-tile softmax stats ----
    float p[8][4], m_r[4], l_r[4];
    #pragma unroll
    for (int r = 0; r < 4; ++r) {
        float mx = s[0][r];
        #pragma unroll
        for (int nt = 1; nt < 8; ++nt) mx = fmaxf(mx, s[nt][r]);
        #pragma unroll
        for (int off = 1; off < 16; off <<= 1) mx = fmaxf(mx, __shfl_xor(mx, off, 64));
        float rs = 0.f;
        #pragma unroll
        for (int nt = 0; nt < 8; ++nt) { p[nt][r] = __expf(s[nt][r] - mx); rs += p[nt][r]; }
        #pragma unroll
        for (int off = 1; off < 16; off <<= 1) rs += __shfl_xor(rs, off, 64);
        m_r[r] = mx; l_r[r] = rs;
    }

    // ---- P -> per-wave LDS (C-layout scatter), read back as A-frags ----
    #pragma unroll
    for (int nt = 0; nt < 8; ++nt)
        #pragma unroll
        for (int r = 0; r < 4; ++r)
            Pl[w][(quad * 4 + r) * PL_STRIDE + nt * 16 + ln15] = f2bf(p[nt][r]);

    bf16x8 ap[4];
    #pragma unroll
    for (int kt = 0; kt < 4; ++kt)
        ap[kt] = *(const bf16x8*)&Pl[w][ln15 * PL_STRIDE + kt * 32 + quad * 8];

    // ---- O_partial = P V (unnormalized) ----
    f32x4 o_acc[4];
    #pragma unroll
    for (int dt = 0; dt < 4; ++dt) o_acc[dt] = (f32x4){0.f, 0.f, 0.f, 0.f};
    #pragma unroll
    for (int dt = 0; dt < 4; ++dt) {
        #pragma unroll
        for (int kt = 0; kt < 4; ++kt) {
            bf16x8 bv;
            #pragma unroll
            for (int jj = 0; jj < 8; ++jj)
                bv[jj] = Vn[(kt * 32 + quad * 8 + jj) * VN_STRIDE + dt * 16 + ln15];
            o_acc[dt] = __builtin_amdgcn_mfma_f32_16x16x32_bf16(ap[kt], bv, o_acc[dt], 0, 0, 0);
        }
    }

    // ---- write partials ----
    #pragma unroll
    for (int dt = 0; dt < 4; ++dt)
        #pragma unroll
        for (int r = 0; r < 4; ++r) {
            const int i = i0w + quad * 4 + r;
            Opart[((size_t)(b * NTOK) + i) * HID + h * HD + dt * 16 + ln15] = o_acc[dt][r];
        }
    if (ln15 == 0) {
        #pragma unroll
        for (int r = 0; r < 4; ++r) {
            const int i = i0w + quad * 4 + r;
            float* mlp = mlbuf + (((size_t)(js * BATCH + b) * NTOK + i) * HEADS + h) * 2;
            mlp[0] = m_r[r]; mlp[1] = l_r[r];
        }
    }
}

// ---------------------------------------------------------------------------
// Stage D: merge attention partials + out = O@Wo + bo. 256 blocks x 4 rows.
// ---------------------------------------------------------------------------
__global__ __launch_bounds__(256) void pga_outproj(
    const float* __restrict__ op0, const float* __restrict__ op1,
    const float* __restrict__ op2, const float* __restrict__ op3,
    const float* __restrict__ mlbuf,
    const float* __restrict__ Wo, const float* __restrict__ bo,
    float* __restrict__ out)
{
    __shared__ float xs[4][HID];
    const int m0 = blockIdx.x * 4;
    const int t = threadIdx.x;
    const int c = t;
    const int h = c >> 6;

    const float* ops[4] = {op0, op1, op2, op3};

    #pragma unroll
    for (int r = 0; r < 4; ++r) {
        const int ig = m0 + r;
        const int b = ig >> 9, i = ig & 511;
        float po[4], ms[4], ls[4];
        #pragma unroll
        for (int s = 0; s < 4; ++s) {
            po[s] = ops[s][(size_t)ig * HID + c];
            const float* mlp = mlbuf + (((size_t)(s * BATCH + b) * NTOK + i) * HEADS + h) * 2;
            ms[s] = mlp[0]; ls[s] = mlp[1];
        }
        const float mmax = fmaxf(fmaxf(ms[0], ms[1]), fmaxf(ms[2], ms[3]));
        float L = 0.f, val = 0.f;
        #pragma unroll
        for (int s = 0; s < 4; ++s) {
            const float e = __expf(ms[s] - mmax);
            L += ls[s] * e;
            val = fmaf(po[s], e, val);
        }
        xs[r][c] = val / L;
    }
    __syncthreads();

    const int cg = t & 63;
    const int rg = t >> 6;
    float4 acc = ((const float4*)bo)[cg];

    const float4* W4 = (const float4*)Wo;
    const float4* xrow = (const float4*)xs[rg];
    #pragma unroll 4
    for (int kq = 0; kq < 64; ++kq) {
        const float4 w0 = W4[(4 * kq + 0) * 64 + cg];
        const float4 w1 = W4[(4 * kq + 1) * 64 + cg];
        const float4 w2 = W4[(4 * kq + 2) * 64 + cg];
        const float4 w3 = W4[(4 * kq + 3) * 64 + cg];
        const float4 xv = xrow[kq];
        acc.x = fmaf(xv.x, w0.x, fmaf(xv.y, w1.x, fmaf(xv.z, w2.x, fmaf(xv.w, w3.x, acc.x))));
        acc.y = fmaf(xv.x, w0.y, fmaf(xv.y, w1.y, fmaf(xv.z, w2.y, fmaf(xv.w, w3.y, acc.y))));
        acc.z = fmaf(xv.x, w0.z, fmaf(xv.y, w1.z, fmaf(xv.z, w2.z, fmaf(xv.w, w3.z, acc.z))));
        acc.w = fmaf(xv.x, w0.w, fmaf(xv.y, w1.w, fmaf(xv.z, w2.w, fmaf(xv.w, w3.w, acc.w))));
    }
    ((float4*)(out + (m0 + rg) * HID))[cg] = acc;
}

extern "C" void kernel_launch(void* const* d_in, const int* in_sizes, int n_in,
                              void* d_out, int out_size, void* d_ws, size_t ws_size,
                              hipStream_t stream) {
    const float* x   = (const float*)d_in[0];
    const int*   adj = (const int*)d_in[1];
    const float* Wq  = (const float*)d_in[2];
    const float* bq  = (const float*)d_in[3];
    const float* Wk  = (const float*)d_in[4];
    const float* bk  = (const float*)d_in[5];
    const float* Wv  = (const float*)d_in[6];
    const float* bv  = (const float*)d_in[7];
    const float* Wo  = (const float*)d_in[8];
    const float* bo  = (const float*)d_in[9];
    const float* Wp1 = (const float*)d_in[10];
    const float* bp1 = (const float*)d_in[11];
    const float* Wp2 = (const float*)d_in[12];
    const float* bp2 = (const float*)d_in[13];
    float* out = (float*)d_out;

    // ws layout (floats), ~14.3 MB. Qb/Kb/Vb are bf16 (131072 floats each).
    // A/BbT die after pga_bias and are reused as Opart[0]/Opart[1].
    float* ws   = (float*)d_ws;
    unsigned short* Qb = (unsigned short*)ws;                    // 512 KB
    unsigned short* Kb = (unsigned short*)(ws + 131072);
    unsigned short* Vb = (unsigned short*)(ws + 262144);
    float* A    = ws + 393216;         // -> Opart[0]
    float* BbT  = ws + 655360;         // -> Opart[1]
    float* bias = ws + 917504;         // 2097152 floats
    float* Op2  = ws + 3014656;
    float* Op3  = Op2 + 262144;
    float* mlb  = Op3 + 262144;        // 32768 floats

    pga_proj5<<<dim3(128, 5), 256, 0, stream>>>(x, Wq, bq, Wk, bk, Wv, bv,
                                                Wp1, bp1, Qb, Kb, Vb, A, BbT);
    pga_bias<<<1024, 640, 0, stream>>>(A, BbT, Wp2, bp2, adj, bias);
    pga_attn<<<256, 256, 0, stream>>>(Qb, Kb, Vb, bias, A, BbT, Op2, Op3, mlb);
    pga_outproj<<<256, 256, 0, stream>>>(A, BbT, Op2, Op3, mlb, Wo, bo, out);
}

// Round 12
// 167.563 us; speedup vs baseline: 1.0543x; 1.0543x over previous
//
#include <hip/hip_runtime.h>
#include <hip/hip_bf16.h>
#include <math.h>

#define NTOK 512      // N
#define BATCH 2
#define HID 256
#define HEADS 4
#define HD 64
#define NEG_INF -1e9f

typedef short bf16x8 __attribute__((ext_vector_type(8)));
typedef short bf16x4 __attribute__((ext_vector_type(4)));
typedef float f32x4 __attribute__((ext_vector_type(4)));

__device__ __forceinline__ short f2bf(float f) {
    union { __hip_bfloat16 h; short s; } u;
    u.h = __float2bfloat16(f);
    return u.s;
}

// tanh-form gelu, exp2+rcp based (8 ops, 2 trans).
__device__ __forceinline__ float fast_gelu(float x) {
    const float x2 = x * x;
    const float u = x * fmaf(x2, 0.044715f, 1.0f);
    const float e = __builtin_amdgcn_exp2f(u * 2.3021176f);
    const float r = __builtin_amdgcn_rcpf(e + 1.0f);
    return fmaf(-x, r, x);
}

// ---------------------------------------------------------------------------
// Stage A: fused 5-way projection GEMM. 8-row tiles, grid (128,5).
//   Q/K/V stored bf16 (attn consumes bf16 anyway); A/BbT stay fp32.
// ---------------------------------------------------------------------------
__global__ __launch_bounds__(256) void pga_proj5(
    const float* __restrict__ x,
    const float* __restrict__ Wq, const float* __restrict__ bq,
    const float* __restrict__ Wk, const float* __restrict__ bk,
    const float* __restrict__ Wv, const float* __restrict__ bv,
    const float* __restrict__ Wp1, const float* __restrict__ bp1,
    unsigned short* __restrict__ Qb, unsigned short* __restrict__ Kb,
    unsigned short* __restrict__ Vb,
    float* __restrict__ A, float* __restrict__ BbT)
{
    __shared__ float xs[8][HID];
    const int m0 = blockIdx.x * 8;
    const int which = blockIdx.y;
    const int t = threadIdx.x;
    const int cg = t & 63;
    const int rg = t >> 6;

    {
        const float4* xg = (const float4*)(x + m0 * HID);
        float4* xsv = (float4*)xs;
        xsv[t] = xg[t];
        xsv[t + 256] = xg[t + 256];
    }
    __syncthreads();

    const float* W; const float* bvec;
    switch (which) {
        case 0: W = Wq; bvec = bq; break;
        case 1: W = Wk; bvec = bk; break;
        case 2: W = Wv; bvec = bv; break;
        case 3: W = Wp1; bvec = bp1; break;
        default: W = Wp1 + HID * HID; bvec = nullptr; break;
    }

    float4 bias4 = make_float4(0.f, 0.f, 0.f, 0.f);
    if (bvec) bias4 = ((const float4*)bvec)[cg];
    float4 acc[2] = {bias4, bias4};

    const float4* W4 = (const float4*)W;
    #pragma unroll 2
    for (int kq = 0; kq < 64; ++kq) {
        const float4 w0 = W4[(4 * kq + 0) * 64 + cg];
        const float4 w1 = W4[(4 * kq + 1) * 64 + cg];
        const float4 w2 = W4[(4 * kq + 2) * 64 + cg];
        const float4 w3 = W4[(4 * kq + 3) * 64 + cg];
        #pragma unroll
        for (int r = 0; r < 2; ++r) {
            const float4 xv = ((const float4*)xs[2 * rg + r])[kq];
            acc[r].x = fmaf(xv.x, w0.x, fmaf(xv.y, w1.x, fmaf(xv.z, w2.x, fmaf(xv.w, w3.x, acc[r].x))));
            acc[r].y = fmaf(xv.x, w0.y, fmaf(xv.y, w1.y, fmaf(xv.z, w2.y, fmaf(xv.w, w3.y, acc[r].y))));
            acc[r].z = fmaf(xv.x, w0.z, fmaf(xv.y, w1.z, fmaf(xv.z, w2.z, fmaf(xv.w, w3.z, acc[r].z))));
            acc[r].w = fmaf(xv.x, w0.w, fmaf(xv.y, w1.w, fmaf(xv.z, w2.w, fmaf(xv.w, w3.w, acc[r].w))));
        }
    }

    if (which < 3) {
        unsigned short* ob = (which == 0) ? Qb : (which == 1) ? Kb : Vb;
        #pragma unroll
        for (int r = 0; r < 2; ++r) {
            bf16x4 v;
            v[0] = f2bf(acc[r].x); v[1] = f2bf(acc[r].y);
            v[2] = f2bf(acc[r].z); v[3] = f2bf(acc[r].w);
            *(bf16x4*)&ob[(m0 + 2 * rg + r) * HID + 4 * cg] = v;
        }
    } else if (which == 3) {
        #pragma unroll
        for (int r = 0; r < 2; ++r)
            ((float4*)(A + (m0 + 2 * rg + r) * HID))[cg] = acc[r];
    } else {
        const int b = m0 >= NTOK;
        const int n0 = m0 - b * NTOK;
        #pragma unroll
        for (int r = 0; r < 2; ++r) {
            const int row = n0 + 2 * rg + r;
            float* ob = BbT + b * (HID * NTOK);
            ob[(4 * cg + 0) * NTOK + row] = acc[r].x;
            ob[(4 * cg + 1) * NTOK + row] = acc[r].y;
            ob[(4 * cg + 2) * NTOK + row] = acc[r].z;
            ob[(4 * cg + 3) * NTOK + row] = acc[r].w;
        }
    }
}

// ---------------------------------------------------------------------------
// Stage B: physics bias. ONE row per 320-thread block (R9/R10 structure —
//   proven fastest). Bias layout is [B][N][N][H]: ONE float4 store per pair
//   (was 4 scattered 4B stores to 4 planes). NEG_INF baked for masked pairs.
// ---------------------------------------------------------------------------
__global__ __launch_bounds__(320) void pga_bias(
    const float* __restrict__ A, const float* __restrict__ BbT,
    const float* __restrict__ Wp2, const float* __restrict__ bp2,
    const int* __restrict__ adj, float* __restrict__ biasg)
{
    __shared__ float as[HID];
    __shared__ float4 wp[HID];
    __shared__ short jlist[NTOK];
    __shared__ int ccnt[8];

    const int t = threadIdx.x;          // 0..319
    const int b = blockIdx.x >> 9;
    const int i = blockIdx.x & 511;
    const int w = t >> 6, lane = t & 63;
    const unsigned long long ltm = (1ull << lane) - 1ull;

    if (t < HID) {
        as[t] = A[(b * NTOK + i) * HID + t];
        wp[t] = ((const float4*)Wp2)[t];
    }

    float4* const obase = (float4*)biasg + ((size_t)(b * NTOK + i)) * NTOK;
    const float4 ninf4 = make_float4(NEG_INF, NEG_INF, NEG_INF, NEG_INF);

    // ---- ordered ballot compaction of row i; NEG_INF to invalid entries ----
    const int c0 = w, c1 = w + 5;       // chunk ids (c1 valid only for w<3)
    const bool m0 = adj[i * NTOK + c0 * 64 + lane] > 0;
    const bool m1 = (c1 < 8) ? (adj[i * NTOK + c1 * 64 + lane] > 0) : true;
    const unsigned long long bm0 = __ballot(m0);
    const unsigned long long bm1 = __ballot(m1);
    if (lane == 0) {
        ccnt[c0] = __popcll(bm0);
        if (c1 < 8) ccnt[c1] = __popcll(bm1);
    }
    if (!m0) obase[c0 * 64 + lane] = ninf4;
    if (c1 < 8 && !m1) obase[c1 * 64 + lane] = ninf4;
    __syncthreads();

    int pref0 = 0, pref1 = 0, tot = 0;
    #pragma unroll
    for (int c = 0; c < 8; ++c) {
        if (c == c0) pref0 = tot;
        if (c == c1) pref1 = tot;
        tot += ccnt[c];
    }
    if (m0) jlist[pref0 + __popcll(bm0 & ltm)] = (short)(c0 * 64 + lane);
    if (c1 < 8 && m1) jlist[pref1 + __popcll(bm1 & ltm)] = (short)(c1 * 64 + lane);
    __syncthreads();

    // ---- main: one valid pair per lane, single pass (tot <= 320 w.h.p.) ----
    const float* bb = BbT + b * (HID * NTOK);
    const float4 bp = *(const float4*)bp2;

    for (int idx = t; idx < tot; idx += 320) {
        const int j = jlist[idx];
        float ah0 = 0.f, ah1 = 0.f, ah2 = 0.f, ah3 = 0.f;
        #pragma unroll 4
        for (int d = 0; d < HID; ++d) {
            const float g = fast_gelu(as[d] + bb[d * NTOK + j]);
            const float4 wv = wp[d];
            ah0 = fmaf(g, wv.x, ah0); ah1 = fmaf(g, wv.y, ah1);
            ah2 = fmaf(g, wv.z, ah2); ah3 = fmaf(g, wv.w, ah3);
        }
        obase[j] = make_float4(ah0 + bp.x, ah1 + bp.y, ah2 + bp.z, ah3 + bp.w);
    }
}

// ---------------------------------------------------------------------------
// Stage C: MFMA attention, flash-decoding j-split. bf16 Q/K/V inputs.
//   Bias layout [B][N][N][H] (NEG_INF baked) -> no adj read.
// ---------------------------------------------------------------------------
#define KT_STRIDE 72
#define VN_STRIDE 76
#define PL_STRIDE 136

__global__ __launch_bounds__(256) void pga_attn(
    const unsigned short* __restrict__ Qb, const unsigned short* __restrict__ Kb,
    const unsigned short* __restrict__ Vb, const float* __restrict__ biasg,
    float* __restrict__ op0, float* __restrict__ op1,
    float* __restrict__ op2, float* __restrict__ op3,
    float* __restrict__ mlbuf)
{
    __shared__ short Kt[128 * KT_STRIDE];
    __shared__ short Vn[128 * VN_STRIDE];
    __shared__ short Pl[4][16 * PL_STRIDE];

    const int blk = blockIdx.x;
    const int js = blk & 3;
    const int qt = (blk >> 2) & 7;
    const int h  = (blk >> 5) & 3;
    const int b  = blk >> 7;
    const int t = threadIdx.x;
    const int w = t >> 6;
    const int lane = t & 63;
    const int ln15 = lane & 15;
    const int quad = lane >> 4;

    float* Opart = (js == 0) ? op0 : (js == 1) ? op1 : (js == 2) ? op2 : op3;
    const int j0 = js * 128;
    const int i0w = qt * 64 + w * 16;

    // ---- Q A-fragments: two direct 16B bf16 loads ----
    const unsigned short* qrow = Qb + ((size_t)(b * NTOK) + i0w + ln15) * HID + h * HD;
    const bf16x8 aq0 = *(const bf16x8*)&qrow[quad * 8];
    const bf16x8 aq1 = *(const bf16x8*)&qrow[32 + quad * 8];

    // ---- stage K (16B copies) and V (8B copies) ----
    #pragma unroll
    for (int k = 0; k < 4; ++k) {
        const int flat8 = k * 256 + t;          // 1024 short8 = 128 rows x 8
        const int jl = flat8 >> 3, d8 = flat8 & 7;
        *(bf16x8*)&Kt[jl * KT_STRIDE + d8 * 8] =
            *(const bf16x8*)&Kb[((size_t)(b * NTOK) + j0 + jl) * HID + h * HD + d8 * 8];
    }
    #pragma unroll
    for (int k = 0; k < 8; ++k) {
        const int flat4 = k * 256 + t;          // 2048 short4 = 128 rows x 16
        const int jl = flat4 >> 4, d4 = flat4 & 15;
        *(bf16x4*)&Vn[jl * VN_STRIDE + d4 * 4] =
            *(const bf16x4*)&Vb[((size_t)(b * NTOK) + j0 + jl) * HID + h * HD + d4 * 4];
    }
    __syncthreads();

    // ---- S = (Q K^T) * scale + bias (bias has NEG_INF baked in) ----
    const float* bgb = biasg + (size_t)b * NTOK * NTOK * 4 + h;
    f32x4 s[8];
    #pragma unroll
    for (int nt = 0; nt < 8; ++nt) {
        const int krow = nt * 16 + ln15;
        const bf16x8 bk0 = *(const bf16x8*)&Kt[krow * KT_STRIDE + quad * 8];
        const bf16x8 bk1 = *(const bf16x8*)&Kt[krow * KT_STRIDE + 32 + quad * 8];
        f32x4 acc = (f32x4){0.f, 0.f, 0.f, 0.f};
        acc = __builtin_amdgcn_mfma_f32_16x16x32_bf16(aq0, bk0, acc, 0, 0, 0);
        acc = __builtin_amdgcn_mfma_f32_16x16x32_bf16(aq1, bk1, acc, 0, 0, 0);
        const int j = j0 + nt * 16 + ln15;
        #pragma unroll
        for (int r = 0; r < 4; ++r) {
            const int i = i0w + quad * 4 + r;
            acc[r] = fmaf(acc[r], 0.125f, bgb[((size_t)i * NTOK + j) * 4]);
        }
        s[nt] = acc;
    }

    // ---- single-tile softmax stats ----
    float p[8][4], m_r[4], l_r[4];
    #pragma unroll
    for (int r = 0; r < 4; ++r) {
        float mx = s[0][r];
        #pragma unroll
        for (int nt = 1; nt < 8; ++nt) mx = fmaxf(mx, s[nt][r]);
        #pragma unroll
        for (int off = 1; off < 16; off <<= 1) mx = fmaxf(mx, __shfl_xor(mx, off, 64));
        float rs = 0.f;
        #pragma unroll
        for (int nt = 0; nt < 8; ++nt) { p[nt][r] = __expf(s[nt][r] - mx); rs += p[nt][r]; }
        #pragma unroll
        for (int off = 1; off < 16; off <<= 1) rs += __shfl_xor(rs, off, 64);
        m_r[r] = mx; l_r[r] = rs;
    }

    // ---- P -> per-wave LDS (C-layout scatter), read back as A-frags ----
    #pragma unroll
    for (int nt = 0; nt < 8; ++nt)
        #pragma unroll
        for (int r = 0; r < 4; ++r)
            Pl[w][(quad * 4 + r) * PL_STRIDE + nt * 16 + ln15] = f2bf(p[nt][r]);

    bf16x8 ap[4];
    #pragma unroll
    for (int kt = 0; kt < 4; ++kt)
        ap[kt] = *(const bf16x8*)&Pl[w][ln15 * PL_STRIDE + kt * 32 + quad * 8];

    // ---- O_partial = P V (unnormalized) ----
    f32x4 o_acc[4];
    #pragma unroll
    for (int dt = 0; dt < 4; ++dt) o_acc[dt] = (f32x4){0.f, 0.f, 0.f, 0.f};
    #pragma unroll
    for (int dt = 0; dt < 4; ++dt) {
        #pragma unroll
        for (int kt = 0; kt < 4; ++kt) {
            bf16x8 bv;
            #pragma unroll
            for (int jj = 0; jj < 8; ++jj)
                bv[jj] = Vn[(kt * 32 + quad * 8 + jj) * VN_STRIDE + dt * 16 + ln15];
            o_acc[dt] = __builtin_amdgcn_mfma_f32_16x16x32_bf16(ap[kt], bv, o_acc[dt], 0, 0, 0);
        }
    }

    // ---- write partials ----
    #pragma unroll
    for (int dt = 0; dt < 4; ++dt)
        #pragma unroll
        for (int r = 0; r < 4; ++r) {
            const int i = i0w + quad * 4 + r;
            Opart[((size_t)(b * NTOK) + i) * HID + h * HD + dt * 16 + ln15] = o_acc[dt][r];
        }
    if (ln15 == 0) {
        #pragma unroll
        for (int r = 0; r < 4; ++r) {
            const int i = i0w + quad * 4 + r;
            float* mlp = mlbuf + (((size_t)(js * BATCH + b) * NTOK + i) * HEADS + h) * 2;
            mlp[0] = m_r[r]; mlp[1] = l_r[r];
        }
    }
}

// ---------------------------------------------------------------------------
// Stage D: merge attention partials + out = O@Wo + bo. 256 blocks x 4 rows.
// ---------------------------------------------------------------------------
__global__ __launch_bounds__(256) void pga_outproj(
    const float* __restrict__ op0, const float* __restrict__ op1,
    const float* __restrict__ op2, const float* __restrict__ op3,
    const float* __restrict__ mlbuf,
    const float* __restrict__ Wo, const float* __restrict__ bo,
    float* __restrict__ out)
{
    __shared__ float xs[4][HID];
    const int m0 = blockIdx.x * 4;
    const int t = threadIdx.x;
    const int c = t;
    const int h = c >> 6;

    const float* ops[4] = {op0, op1, op2, op3};

    #pragma unroll
    for (int r = 0; r < 4; ++r) {
        const int ig = m0 + r;
        const int b = ig >> 9, i = ig & 511;
        float po[4], ms[4], ls[4];
        #pragma unroll
        for (int s = 0; s < 4; ++s) {
            po[s] = ops[s][(size_t)ig * HID + c];
            const float* mlp = mlbuf + (((size_t)(s * BATCH + b) * NTOK + i) * HEADS + h) * 2;
            ms[s] = mlp[0]; ls[s] = mlp[1];
        }
        const float mmax = fmaxf(fmaxf(ms[0], ms[1]), fmaxf(ms[2], ms[3]));
        float L = 0.f, val = 0.f;
        #pragma unroll
        for (int s = 0; s < 4; ++s) {
            const float e = __expf(ms[s] - mmax);
            L += ls[s] * e;
            val = fmaf(po[s], e, val);
        }
        xs[r][c] = val / L;
    }
    __syncthreads();

    const int cg = t & 63;
    const int rg = t >> 6;
    float4 acc = ((const float4*)bo)[cg];

    const float4* W4 = (const float4*)Wo;
    const float4* xrow = (const float4*)xs[rg];
    #pragma unroll 4
    for (int kq = 0; kq < 64; ++kq) {
        const float4 w0 = W4[(4 * kq + 0) * 64 + cg];
        const float4 w1 = W4[(4 * kq + 1) * 64 + cg];
        const float4 w2 = W4[(4 * kq + 2) * 64 + cg];
        const float4 w3 = W4[(4 * kq + 3) * 64 + cg];
        const float4 xv = xrow[kq];
        acc.x = fmaf(xv.x, w0.x, fmaf(xv.y, w1.x, fmaf(xv.z, w2.x, fmaf(xv.w, w3.x, acc.x))));
        acc.y = fmaf(xv.x, w0.y, fmaf(xv.y, w1.y, fmaf(xv.z, w2.y, fmaf(xv.w, w3.y, acc.y))));
        acc.z = fmaf(xv.x, w0.z, fmaf(xv.y, w1.z, fmaf(xv.z, w2.z, fmaf(xv.w, w3.z, acc.z))));
        acc.w = fmaf(xv.x, w0.w, fmaf(xv.y, w1.w, fmaf(xv.z, w2.w, fmaf(xv.w, w3.w, acc.w))));
    }
    ((float4*)(out + (m0 + rg) * HID))[cg] = acc;
}

extern "C" void kernel_launch(void* const* d_in, const int* in_sizes, int n_in,
                              void* d_out, int out_size, void* d_ws, size_t ws_size,
                              hipStream_t stream) {
    const float* x   = (const float*)d_in[0];
    const int*   adj = (const int*)d_in[1];
    const float* Wq  = (const float*)d_in[2];
    const float* bq  = (const float*)d_in[3];
    const float* Wk  = (const float*)d_in[4];
    const float* bk  = (const float*)d_in[5];
    const float* Wv  = (const float*)d_in[6];
    const float* bv  = (const float*)d_in[7];
    const float* Wo  = (const float*)d_in[8];
    const float* bo  = (const float*)d_in[9];
    const float* Wp1 = (const float*)d_in[10];
    const float* bp1 = (const float*)d_in[11];
    const float* Wp2 = (const float*)d_in[12];
    const float* bp2 = (const float*)d_in[13];
    float* out = (float*)d_out;

    // ws layout (floats), ~14.3 MB. Qb/Kb/Vb are bf16 (131072 floats each).
    // A/BbT die after pga_bias and are reused as Opart[0]/Opart[1].
    // bias is [B][N][N][H] float4-per-pair.
    float* ws   = (float*)d_ws;
    unsigned short* Qb = (unsigned short*)ws;                    // 512 KB
    unsigned short* Kb = (unsigned short*)(ws + 131072);
    unsigned short* Vb = (unsigned short*)(ws + 262144);
    float* A    = ws + 393216;         // -> Opart[0]
    float* BbT  = ws + 655360;         // -> Opart[1]
    float* bias = ws + 917504;         // 2097152 floats
    float* Op2  = ws + 3014656;
    float* Op3  = Op2 + 262144;
    float* mlb  = Op3 + 262144;        // 32768 floats

    pga_proj5<<<dim3(128, 5), 256, 0, stream>>>(x, Wq, bq, Wk, bk, Wv, bv,
                                                Wp1, bp1, Qb, Kb, Vb, A, BbT);
    pga_bias<<<1024, 320, 0, stream>>>(A, BbT, Wp2, bp2, adj, bias);
    pga_attn<<<256, 256, 0, stream>>>(Qb, Kb, Vb, bias, A, BbT, Op2, Op3, mlb);
    pga_outproj<<<256, 256, 0, stream>>>(A, BbT, Op2, Op3, mlb, Wo, bo, out);
}

// Round 13
// 166.434 us; speedup vs baseline: 1.0614x; 1.0068x over previous
//
#include <hip/hip_runtime.h>
#include <hip/hip_bf16.h>
#include <math.h>

#define NTOK 512      // N
#define BATCH 2
#define HID 256
#define HEADS 4
#define HD 64
#define NEG_INF -1e9f

typedef short bf16x8 __attribute__((ext_vector_type(8)));
typedef short bf16x4 __attribute__((ext_vector_type(4)));
typedef float f32x4 __attribute__((ext_vector_type(4)));

__device__ __forceinline__ short f2bf(float f) {
    union { __hip_bfloat16 h; short s; } u;
    u.h = __float2bfloat16(f);
    return u.s;
}

// tanh-form gelu, exp2+rcp based (8 ops, 2 trans).
__device__ __forceinline__ float fast_gelu(float x) {
    const float x2 = x * x;
    const float u = x * fmaf(x2, 0.044715f, 1.0f);
    const float e = __builtin_amdgcn_exp2f(u * 2.3021176f);
    const float r = __builtin_amdgcn_rcpf(e + 1.0f);
    return fmaf(-x, r, x);
}

// ---------------------------------------------------------------------------
// Stage A: fused 5-way projection GEMM. 8-row tiles, grid (128,5).
//   Q/K/V stored bf16; A and Bb both stored row-major fp32 (Bb no longer
//   transposed -> which==4 gets the same coalesced float4 store as A).
// ---------------------------------------------------------------------------
__global__ __launch_bounds__(256) void pga_proj5(
    const float* __restrict__ x,
    const float* __restrict__ Wq, const float* __restrict__ bq,
    const float* __restrict__ Wk, const float* __restrict__ bk,
    const float* __restrict__ Wv, const float* __restrict__ bv,
    const float* __restrict__ Wp1, const float* __restrict__ bp1,
    unsigned short* __restrict__ Qb, unsigned short* __restrict__ Kb,
    unsigned short* __restrict__ Vb,
    float* __restrict__ A, float* __restrict__ Bb)
{
    __shared__ float xs[8][HID];
    const int m0 = blockIdx.x * 8;
    const int which = blockIdx.y;
    const int t = threadIdx.x;
    const int cg = t & 63;
    const int rg = t >> 6;

    {
        const float4* xg = (const float4*)(x + m0 * HID);
        float4* xsv = (float4*)xs;
        xsv[t] = xg[t];
        xsv[t + 256] = xg[t + 256];
    }
    __syncthreads();

    const float* W; const float* bvec;
    switch (which) {
        case 0: W = Wq; bvec = bq; break;
        case 1: W = Wk; bvec = bk; break;
        case 2: W = Wv; bvec = bv; break;
        case 3: W = Wp1; bvec = bp1; break;
        default: W = Wp1 + HID * HID; bvec = nullptr; break;
    }

    float4 bias4 = make_float4(0.f, 0.f, 0.f, 0.f);
    if (bvec) bias4 = ((const float4*)bvec)[cg];
    float4 acc[2] = {bias4, bias4};

    const float4* W4 = (const float4*)W;
    #pragma unroll 2
    for (int kq = 0; kq < 64; ++kq) {
        const float4 w0 = W4[(4 * kq + 0) * 64 + cg];
        const float4 w1 = W4[(4 * kq + 1) * 64 + cg];
        const float4 w2 = W4[(4 * kq + 2) * 64 + cg];
        const float4 w3 = W4[(4 * kq + 3) * 64 + cg];
        #pragma unroll
        for (int r = 0; r < 2; ++r) {
            const float4 xv = ((const float4*)xs[2 * rg + r])[kq];
            acc[r].x = fmaf(xv.x, w0.x, fmaf(xv.y, w1.x, fmaf(xv.z, w2.x, fmaf(xv.w, w3.x, acc[r].x))));
            acc[r].y = fmaf(xv.x, w0.y, fmaf(xv.y, w1.y, fmaf(xv.z, w2.y, fmaf(xv.w, w3.y, acc[r].y))));
            acc[r].z = fmaf(xv.x, w0.z, fmaf(xv.y, w1.z, fmaf(xv.z, w2.z, fmaf(xv.w, w3.z, acc[r].z))));
            acc[r].w = fmaf(xv.x, w0.w, fmaf(xv.y, w1.w, fmaf(xv.z, w2.w, fmaf(xv.w, w3.w, acc[r].w))));
        }
    }

    if (which < 3) {
        unsigned short* ob = (which == 0) ? Qb : (which == 1) ? Kb : Vb;
        #pragma unroll
        for (int r = 0; r < 2; ++r) {
            bf16x4 v;
            v[0] = f2bf(acc[r].x); v[1] = f2bf(acc[r].y);
            v[2] = f2bf(acc[r].z); v[3] = f2bf(acc[r].w);
            *(bf16x4*)&ob[(m0 + 2 * rg + r) * HID + 4 * cg] = v;
        }
    } else {
        float* outf = (which == 3) ? A : Bb;
        #pragma unroll
        for (int r = 0; r < 2; ++r)
            ((float4*)(outf + (m0 + 2 * rg + r) * HID))[cg] = acc[r];
    }
}

// ---------------------------------------------------------------------------
// Stage B: physics bias. ONE row per 320-thread block (proven structure).
//   Bb is row-major [b][j][d]: each lane STREAMS its pair's 1KB row via 64
//   sequential float4 loads (replaces 256 scalar stride-2KB gather loads).
//   Bias output [B][N][N][H]: one float4 store per pair; NEG_INF baked.
// ---------------------------------------------------------------------------
__global__ __launch_bounds__(320) void pga_bias(
    const float* __restrict__ A, const float* __restrict__ Bb,
    const float* __restrict__ Wp2, const float* __restrict__ bp2,
    const int* __restrict__ adj, float* __restrict__ biasg)
{
    __shared__ float as[HID];
    __shared__ float4 wp[HID];
    __shared__ short jlist[NTOK];
    __shared__ int ccnt[8];

    const int t = threadIdx.x;          // 0..319
    const int b = blockIdx.x >> 9;
    const int i = blockIdx.x & 511;
    const int w = t >> 6, lane = t & 63;
    const unsigned long long ltm = (1ull << lane) - 1ull;

    if (t < HID) {
        as[t] = A[(b * NTOK + i) * HID + t];
        wp[t] = ((const float4*)Wp2)[t];
    }

    float4* const obase = (float4*)biasg + ((size_t)(b * NTOK + i)) * NTOK;
    const float4 ninf4 = make_float4(NEG_INF, NEG_INF, NEG_INF, NEG_INF);

    // ---- ordered ballot compaction of row i; NEG_INF to invalid entries ----
    const int c0 = w, c1 = w + 5;       // chunk ids (c1 valid only for w<3)
    const bool m0 = adj[i * NTOK + c0 * 64 + lane] > 0;
    const bool m1 = (c1 < 8) ? (adj[i * NTOK + c1 * 64 + lane] > 0) : true;
    const unsigned long long bm0 = __ballot(m0);
    const unsigned long long bm1 = __ballot(m1);
    if (lane == 0) {
        ccnt[c0] = __popcll(bm0);
        if (c1 < 8) ccnt[c1] = __popcll(bm1);
    }
    if (!m0) obase[c0 * 64 + lane] = ninf4;
    if (c1 < 8 && !m1) obase[c1 * 64 + lane] = ninf4;
    __syncthreads();

    int pref0 = 0, pref1 = 0, tot = 0;
    #pragma unroll
    for (int c = 0; c < 8; ++c) {
        if (c == c0) pref0 = tot;
        if (c == c1) pref1 = tot;
        tot += ccnt[c];
    }
    if (m0) jlist[pref0 + __popcll(bm0 & ltm)] = (short)(c0 * 64 + lane);
    if (c1 < 8 && m1) jlist[pref1 + __popcll(bm1 & ltm)] = (short)(c1 * 64 + lane);
    __syncthreads();

    // ---- main: one valid pair per lane; per-lane sequential streaming ----
    const float* bbB = Bb + (size_t)b * NTOK * HID;
    const float4 bp = *(const float4*)bp2;

    for (int idx = t; idx < tot; idx += 320) {
        const int j = jlist[idx];
        const float4* br = (const float4*)(bbB + (size_t)j * HID);
        float ah0 = 0.f, ah1 = 0.f, ah2 = 0.f, ah3 = 0.f;
        #pragma unroll 2
        for (int dq = 0; dq < 64; ++dq) {
            const float4 bv4 = br[dq];
            const float4 av4 = ((const float4*)as)[dq];
            {
                const float g = fast_gelu(av4.x + bv4.x);
                const float4 wv = wp[4 * dq + 0];
                ah0 = fmaf(g, wv.x, ah0); ah1 = fmaf(g, wv.y, ah1);
                ah2 = fmaf(g, wv.z, ah2); ah3 = fmaf(g, wv.w, ah3);
            }
            {
                const float g = fast_gelu(av4.y + bv4.y);
                const float4 wv = wp[4 * dq + 1];
                ah0 = fmaf(g, wv.x, ah0); ah1 = fmaf(g, wv.y, ah1);
                ah2 = fmaf(g, wv.z, ah2); ah3 = fmaf(g, wv.w, ah3);
            }
            {
                const float g = fast_gelu(av4.z + bv4.z);
                const float4 wv = wp[4 * dq + 2];
                ah0 = fmaf(g, wv.x, ah0); ah1 = fmaf(g, wv.y, ah1);
                ah2 = fmaf(g, wv.z, ah2); ah3 = fmaf(g, wv.w, ah3);
            }
            {
                const float g = fast_gelu(av4.w + bv4.w);
                const float4 wv = wp[4 * dq + 3];
                ah0 = fmaf(g, wv.x, ah0); ah1 = fmaf(g, wv.y, ah1);
                ah2 = fmaf(g, wv.z, ah2); ah3 = fmaf(g, wv.w, ah3);
            }
        }
        obase[j] = make_float4(ah0 + bp.x, ah1 + bp.y, ah2 + bp.z, ah3 + bp.w);
    }
}

// ---------------------------------------------------------------------------
// Stage C: MFMA attention, flash-decoding j-split. bf16 Q/K/V inputs.
//   Bias layout [B][N][N][H] (NEG_INF baked) -> no adj read.
// ---------------------------------------------------------------------------
#define KT_STRIDE 72
#define VN_STRIDE 76
#define PL_STRIDE 136

__global__ __launch_bounds__(256) void pga_attn(
    const unsigned short* __restrict__ Qb, const unsigned short* __restrict__ Kb,
    const unsigned short* __restrict__ Vb, const float* __restrict__ biasg,
    float* __restrict__ op0, float* __restrict__ op1,
    float* __restrict__ op2, float* __restrict__ op3,
    float* __restrict__ mlbuf)
{
    __shared__ short Kt[128 * KT_STRIDE];
    __shared__ short Vn[128 * VN_STRIDE];
    __shared__ short Pl[4][16 * PL_STRIDE];

    const int blk = blockIdx.x;
    const int js = blk & 3;
    const int qt = (blk >> 2) & 7;
    const int h  = (blk >> 5) & 3;
    const int b  = blk >> 7;
    const int t = threadIdx.x;
    const int w = t >> 6;
    const int lane = t & 63;
    const int ln15 = lane & 15;
    const int quad = lane >> 4;

    float* Opart = (js == 0) ? op0 : (js == 1) ? op1 : (js == 2) ? op2 : op3;
    const int j0 = js * 128;
    const int i0w = qt * 64 + w * 16;

    // ---- Q A-fragments: two direct 16B bf16 loads ----
    const unsigned short* qrow = Qb + ((size_t)(b * NTOK) + i0w + ln15) * HID + h * HD;
    const bf16x8 aq0 = *(const bf16x8*)&qrow[quad * 8];
    const bf16x8 aq1 = *(const bf16x8*)&qrow[32 + quad * 8];

    // ---- stage K (16B copies) and V (8B copies) ----
    #pragma unroll
    for (int k = 0; k < 4; ++k) {
        const int flat8 = k * 256 + t;          // 1024 short8 = 128 rows x 8
        const int jl = flat8 >> 3, d8 = flat8 & 7;
        *(bf16x8*)&Kt[jl * KT_STRIDE + d8 * 8] =
            *(const bf16x8*)&Kb[((size_t)(b * NTOK) + j0 + jl) * HID + h * HD + d8 * 8];
    }
    #pragma unroll
    for (int k = 0; k < 8; ++k) {
        const int flat4 = k * 256 + t;          // 2048 short4 = 128 rows x 16
        const int jl = flat4 >> 4, d4 = flat4 & 15;
        *(bf16x4*)&Vn[jl * VN_STRIDE + d4 * 4] =
            *(const bf16x4*)&Vb[((size_t)(b * NTOK) + j0 + jl) * HID + h * HD + d4 * 4];
    }
    __syncthreads();

    // ---- S = (Q K^T) * scale + bias (bias has NEG_INF baked in) ----
    const float* bgb = biasg + (size_t)b * NTOK * NTOK * 4 + h;
    f32x4 s[8];
    #pragma unroll
    for (int nt = 0; nt < 8; ++nt) {
        const int krow = nt * 16 + ln15;
        const bf16x8 bk0 = *(const bf16x8*)&Kt[krow * KT_STRIDE + quad * 8];
        const bf16x8 bk1 = *(const bf16x8*)&Kt[krow * KT_STRIDE + 32 + quad * 8];
        f32x4 acc = (f32x4){0.f, 0.f, 0.f, 0.f};
        acc = __builtin_amdgcn_mfma_f32_16x16x32_bf16(aq0, bk0, acc, 0, 0, 0);
        acc = __builtin_amdgcn_mfma_f32_16x16x32_bf16(aq1, bk1, acc, 0, 0, 0);
        const int j = j0 + nt * 16 + ln15;
        #pragma unroll
        for (int r = 0; r < 4; ++r) {
            const int i = i0w + quad * 4 + r;
            acc[r] = fmaf(acc[r], 0.125f, bgb[((size_t)i * NTOK + j) * 4]);
        }
        s[nt] = acc;
    }

    // ---- single-tile softmax stats ----
    float p[8][4], m_r[4], l_r[4];
    #pragma unroll
    for (int r = 0; r < 4; ++r) {
        float mx = s[0][r];
        #pragma unroll
        for (int nt = 1; nt < 8; ++nt) mx = fmaxf(mx, s[nt][r]);
        #pragma unroll
        for (int off = 1; off < 16; off <<= 1) mx = fmaxf(mx, __shfl_xor(mx, off, 64));
        float rs = 0.f;
        #pragma unroll
        for (int nt = 0; nt < 8; ++nt) { p[nt][r] = __expf(s[nt][r] - mx); rs += p[nt][r]; }
        #pragma unroll
        for (int off = 1; off < 16; off <<= 1) rs += __shfl_xor(rs, off, 64);
        m_r[r] = mx; l_r[r] = rs;
    }

    // ---- P -> per-wave LDS (C-layout scatter), read back as A-frags ----
    #pragma unroll
    for (int nt = 0; nt < 8; ++nt)
        #pragma unroll
        for (int r = 0; r < 4; ++r)
            Pl[w][(quad * 4 + r) * PL_STRIDE + nt * 16 + ln15] = f2bf(p[nt][r]);

    bf16x8 ap[4];
    #pragma unroll
    for (int kt = 0; kt < 4; ++kt)
        ap[kt] = *(const bf16x8*)&Pl[w][ln15 * PL_STRIDE + kt * 32 + quad * 8];

    // ---- O_partial = P V (unnormalized) ----
    f32x4 o_acc[4];
    #pragma unroll
    for (int dt = 0; dt < 4; ++dt) o_acc[dt] = (f32x4){0.f, 0.f, 0.f, 0.f};
    #pragma unroll
    for (int dt = 0; dt < 4; ++dt) {
        #pragma unroll
        for (int kt = 0; kt < 4; ++kt) {
            bf16x8 bv;
            #pragma unroll
            for (int jj = 0; jj < 8; ++jj)
                bv[jj] = Vn[(kt * 32 + quad * 8 + jj) * VN_STRIDE + dt * 16 + ln15];
            o_acc[dt] = __builtin_amdgcn_mfma_f32_16x16x32_bf16(ap[kt], bv, o_acc[dt], 0, 0, 0);
        }
    }

    // ---- write partials ----
    #pragma unroll
    for (int dt = 0; dt < 4; ++dt)
        #pragma unroll
        for (int r = 0; r < 4; ++r) {
            const int i = i0w + quad * 4 + r;
            Opart[((size_t)(b * NTOK) + i) * HID + h * HD + dt * 16 + ln15] = o_acc[dt][r];
        }
    if (ln15 == 0) {
        #pragma unroll
        for (int r = 0; r < 4; ++r) {
            const int i = i0w + quad * 4 + r;
            float* mlp = mlbuf + (((size_t)(js * BATCH + b) * NTOK + i) * HEADS + h) * 2;
            mlp[0] = m_r[r]; mlp[1] = l_r[r];
        }
    }
}

// ---------------------------------------------------------------------------
// Stage D: merge attention partials + out = O@Wo + bo. 256 blocks x 4 rows.
// ---------------------------------------------------------------------------
__global__ __launch_bounds__(256) void pga_outproj(
    const float* __restrict__ op0, const float* __restrict__ op1,
    const float* __restrict__ op2, const float* __restrict__ op3,
    const float* __restrict__ mlbuf,
    const float* __restrict__ Wo, const float* __restrict__ bo,
    float* __restrict__ out)
{
    __shared__ float xs[4][HID];
    const int m0 = blockIdx.x * 4;
    const int t = threadIdx.x;
    const int c = t;
    const int h = c >> 6;

    const float* ops[4] = {op0, op1, op2, op3};

    #pragma unroll
    for (int r = 0; r < 4; ++r) {
        const int ig = m0 + r;
        const int b = ig >> 9, i = ig & 511;
        float po[4], ms[4], ls[4];
        #pragma unroll
        for (int s = 0; s < 4; ++s) {
            po[s] = ops[s][(size_t)ig * HID + c];
            const float* mlp = mlbuf + (((size_t)(s * BATCH + b) * NTOK + i) * HEADS + h) * 2;
            ms[s] = mlp[0]; ls[s] = mlp[1];
        }
        const float mmax = fmaxf(fmaxf(ms[0], ms[1]), fmaxf(ms[2], ms[3]));
        float L = 0.f, val = 0.f;
        #pragma unroll
        for (int s = 0; s < 4; ++s) {
            const float e = __expf(ms[s] - mmax);
            L += ls[s] * e;
            val = fmaf(po[s], e, val);
        }
        xs[r][c] = val / L;
    }
    __syncthreads();

    const int cg = t & 63;
    const int rg = t >> 6;
    float4 acc = ((const float4*)bo)[cg];

    const float4* W4 = (const float4*)Wo;
    const float4* xrow = (const float4*)xs[rg];
    #pragma unroll 4
    for (int kq = 0; kq < 64; ++kq) {
        const float4 w0 = W4[(4 * kq + 0) * 64 + cg];
        const float4 w1 = W4[(4 * kq + 1) * 64 + cg];
        const float4 w2 = W4[(4 * kq + 2) * 64 + cg];
        const float4 w3 = W4[(4 * kq + 3) * 64 + cg];
        const float4 xv = xrow[kq];
        acc.x = fmaf(xv.x, w0.x, fmaf(xv.y, w1.x, fmaf(xv.z, w2.x, fmaf(xv.w, w3.x, acc.x))));
        acc.y = fmaf(xv.x, w0.y, fmaf(xv.y, w1.y, fmaf(xv.z, w2.y, fmaf(xv.w, w3.y, acc.y))));
        acc.z = fmaf(xv.x, w0.z, fmaf(xv.y, w1.z, fmaf(xv.z, w2.z, fmaf(xv.w, w3.z, acc.z))));
        acc.w = fmaf(xv.x, w0.w, fmaf(xv.y, w1.w, fmaf(xv.z, w2.w, fmaf(xv.w, w3.w, acc.w))));
    }
    ((float4*)(out + (m0 + rg) * HID))[cg] = acc;
}

extern "C" void kernel_launch(void* const* d_in, const int* in_sizes, int n_in,
                              void* d_out, int out_size, void* d_ws, size_t ws_size,
                              hipStream_t stream) {
    const float* x   = (const float*)d_in[0];
    const int*   adj = (const int*)d_in[1];
    const float* Wq  = (const float*)d_in[2];
    const float* bq  = (const float*)d_in[3];
    const float* Wk  = (const float*)d_in[4];
    const float* bk  = (const float*)d_in[5];
    const float* Wv  = (const float*)d_in[6];
    const float* bv  = (const float*)d_in[7];
    const float* Wo  = (const float*)d_in[8];
    const float* bo  = (const float*)d_in[9];
    const float* Wp1 = (const float*)d_in[10];
    const float* bp1 = (const float*)d_in[11];
    const float* Wp2 = (const float*)d_in[12];
    const float* bp2 = (const float*)d_in[13];
    float* out = (float*)d_out;

    // ws layout (floats), ~14.3 MB. Qb/Kb/Vb are bf16 (131072 floats each).
    // A/Bb die after pga_bias and are reused as Opart[0]/Opart[1].
    // Bb is row-major [b][j][d]; bias is [B][N][N][H] float4-per-pair.
    float* ws   = (float*)d_ws;
    unsigned short* Qb = (unsigned short*)ws;                    // 512 KB
    unsigned short* Kb = (unsigned short*)(ws + 131072);
    unsigned short* Vb = (unsigned short*)(ws + 262144);
    float* A    = ws + 393216;         // -> Opart[0]
    float* Bb   = ws + 655360;         // -> Opart[1]
    float* bias = ws + 917504;         // 2097152 floats
    float* Op2  = ws + 3014656;
    float* Op3  = Op2 + 262144;
    float* mlb  = Op3 + 262144;        // 32768 floats

    pga_proj5<<<dim3(128, 5), 256, 0, stream>>>(x, Wq, bq, Wk, bk, Wv, bv,
                                                Wp1, bp1, Qb, Kb, Vb, A, Bb);
    pga_bias<<<1024, 320, 0, stream>>>(A, Bb, Wp2, bp2, adj, bias);
    pga_attn<<<256, 256, 0, stream>>>(Qb, Kb, Vb, bias, A, Bb, Op2, Op3, mlb);
    pga_outproj<<<256, 256, 0, stream>>>(A, Bb, Op2, Op3, mlb, Wo, bo, out);
}